// Round 9
// baseline (874.192 us; speedup 1.0000x reference)
//
#include <hip/hip_runtime.h>

#define N_NODES 50000
#define N_EDGES 800000
#define N_GRAPHS 1000
#define NODE_DIMC 128
#define HDIM 256
#define NLAYERS 4
#define NPROPS 3
#define BN_EPSF 1e-5f
#define NBLK 196   // ceil(N_NODES/256)
#define GB 8       // graphs per head-block
#define NSLICE 8   // 32-ch slices, XCD-pinned

typedef __attribute__((ext_vector_type(4))) float f32x4;
typedef __attribute__((ext_vector_type(8))) short short8;
typedef __attribute__((ext_vector_type(8))) unsigned short u16x8;

__device__ __forceinline__ float4 ld4(const float* p){ return *reinterpret_cast<const float4*>(p); }
__device__ __forceinline__ unsigned short f2bf(float f){
  unsigned u = __float_as_uint(f);
  return (unsigned short)((u + 0x7FFFu + ((u >> 16) & 1u)) >> 16);
}
__device__ __forceinline__ float bf2f(unsigned short s){ return __uint_as_float(((unsigned)s) << 16); }

__device__ __forceinline__ void gl2lds16(const void* g, void* l){
  __builtin_amdgcn_global_load_lds((const __attribute__((address_space(1))) unsigned int*)g,
                                   (__attribute__((address_space(3))) unsigned int*)l, 16, 0, 0);
}

// ---------------- CSR build ----------------
__global__ void k_count(const int* __restrict__ ei, int* __restrict__ cnt){
  int e = blockIdx.x*256 + threadIdx.x;
  if (e < N_EDGES) atomicAdd(&cnt[ei[N_EDGES + e]], 1);
}

__global__ void k_scan1(const int* __restrict__ cnt, int* __restrict__ rowp, int* __restrict__ part){
  __shared__ int s[256];
  int t = threadIdx.x;
  int i = blockIdx.x*256 + t;
  int v = (i < N_NODES) ? cnt[i] : 0;
  s[t] = v;
  __syncthreads();
  #pragma unroll
  for (int off=1; off<256; off<<=1){
    int x = s[t];
    int y = (t >= off) ? s[t-off] : 0;
    __syncthreads();
    s[t] = x + y;
    __syncthreads();
  }
  if (i < N_NODES) rowp[i+1] = s[t];
  if (t == 255) part[blockIdx.x] = s[255];
}

__global__ void k_scan2(int* __restrict__ part){
  __shared__ int s[256];
  int t = threadIdx.x;
  int v = (t < NBLK) ? part[t] : 0;
  s[t] = v;
  __syncthreads();
  #pragma unroll
  for (int off=1; off<256; off<<=1){
    int x = s[t];
    int y = (t >= off) ? s[t-off] : 0;
    __syncthreads();
    s[t] = x + y;
    __syncthreads();
  }
  if (t < NBLK) part[t] = s[t] - v;   // exclusive offsets
}

__global__ void k_scan3(const int* __restrict__ cnt, int* __restrict__ rowp,
                        const int* __restrict__ part, float* __restrict__ dinv,
                        int* __restrict__ fill){
  int i = blockIdx.x*256 + threadIdx.x;
  if (i < N_NODES){
    rowp[i+1] += part[blockIdx.x];
    dinv[i] = rsqrtf(1.0f + (float)cnt[i]);
    fill[i] = 0;
  }
  if (i == 0) rowp[0] = 0;
}

__global__ void k_fill(const int* __restrict__ ei, const int* __restrict__ rowp, int* __restrict__ fill,
                       const float* __restrict__ dinv, int2* __restrict__ csr){
  int e = blockIdx.x*256 + threadIdx.x;
  if (e >= N_EDGES) return;
  int sr = ei[e];
  int ds = ei[N_EDGES + e];
  int pos = rowp[ds] + atomicAdd(&fill[ds], 1);
  csr[pos] = make_int2(sr, __float_as_int(dinv[sr]));
}

// ---------------- fused prep: x->bf16, embWt, gcnWt, BN fold ----------------
#define XCVT_N (N_NODES*NODE_DIMC/4)
#define EMBWT_N (NODE_DIMC*HDIM)
#define GCNWT_N (NLAYERS*HDIM*HDIM)
#define BN_N (NLAYERS*HDIM)
#define PREP_TOTAL (XCVT_N + EMBWT_N + GCNWT_N + BN_N)

__global__ void k_prep(const float* __restrict__ x, unsigned short* __restrict__ xb,
                       const float* __restrict__ embW, unsigned short* __restrict__ embWt,
                       const float* __restrict__ gcnW, unsigned short* __restrict__ gcnWt,
                       const float* __restrict__ gcnb, const float* __restrict__ bng,
                       const float* __restrict__ bnb, const float* __restrict__ bnm,
                       const float* __restrict__ bnv, float* __restrict__ S, float* __restrict__ T){
  int idx = blockIdx.x*256 + threadIdx.x;
  if (idx < XCVT_N){
    float4 v = ld4(x + (size_t)idx*4);
    ushort4 o;
    o.x = f2bf(v.x); o.y = f2bf(v.y); o.z = f2bf(v.z); o.w = f2bf(v.w);
    *reinterpret_cast<ushort4*>(xb + (size_t)idx*4) = o;
    return;
  }
  idx -= XCVT_N;
  if (idx < EMBWT_N){
    int c = idx >> 7, k = idx & 127;
    embWt[idx] = f2bf(embW[(size_t)k*HDIM + c]);
    return;
  }
  idx -= EMBWT_N;
  if (idx < GCNWT_N){
    int l = idx >> 16, rem = idx & 65535;
    int c = rem >> 8, k = rem & 255;
    gcnWt[idx] = f2bf(gcnW[(size_t)l*HDIM*HDIM + (size_t)k*HDIM + c]);
    return;
  }
  idx -= GCNWT_N;
  if (idx < BN_N){
    float s = bng[idx] * rsqrtf(bnv[idx] + BN_EPSF);
    S[idx] = s;
    T[idx] = (gcnb[idx] - bnm[idx]) * s + bnb[idx];
  }
}

// ---------------- bf16 MFMA GEMM: 128x128 tile, BK=32, dbuf LDS ----------------
// EMB=true: bias+relu, write bf16 h row-major. EMB=false: write bf16 m TILED m_t[ch>>5][node][ch&31].
template<int K, bool EMB>
__global__ __launch_bounds__(256) void k_mgemm(const unsigned short* __restrict__ A,
                                               const unsigned short* __restrict__ Wt,
                                               const float* __restrict__ bias,
                                               unsigned short* __restrict__ outp,
                                               int nrows){
  __shared__ unsigned short As[2][128*32];   // 8KB each
  __shared__ unsigned short Bs[2][128*32];
  const int t = threadIdx.x;
  const int lane = t & 63;
  const int wid = t >> 6;
  const int wm = wid >> 1, wn = wid & 1;
  const int row0 = blockIdx.x * 128;
  const int col0 = blockIdx.y * 128;
  constexpr int NK = K / 32;

  f32x4 acc[4][4];
  #pragma unroll
  for (int i=0;i<4;i++)
    #pragma unroll
    for (int j=0;j<4;j++) acc[i][j] = (f32x4){0.f,0.f,0.f,0.f};

  auto stage = [&](int buf, int k0){
    #pragma unroll
    for (int i=0;i<2;i++){
      int c0 = (wid*2 + i)*64;                  // wave-uniform chunk base (16B units)
      int c  = c0 + lane;
      int cs = c ^ ((c >> 3) & 7);              // pre-swizzled source chunk
      int r  = cs >> 2;
      int kp = (cs & 3) * 8;
      gl2lds16(A + (size_t)(row0 + r)*K + k0 + kp, &As[buf][c0*8]);
    }
    #pragma unroll
    for (int i=0;i<2;i++){
      int c0 = (wid*2 + i)*64;
      int c  = c0 + lane;
      int cs = c ^ ((c >> 3) & 7);
      int r  = cs >> 2;
      int kp = (cs & 3) * 8;
      gl2lds16(Wt + (size_t)(col0 + r)*K + k0 + kp, &Bs[buf][c0*8]);
    }
  };

  stage(0, 0);
  int cur = 0;
  #pragma unroll
  for (int tk = 0; tk < NK; ++tk){
    if (tk + 1 < NK){
      stage(cur ^ 1, (tk+1)*32);
      asm volatile("s_waitcnt vmcnt(4)" ::: "memory");
    } else {
      asm volatile("s_waitcnt vmcnt(0)" ::: "memory");
    }
    __builtin_amdgcn_s_barrier();
    const int kofs = (lane >> 4) * 8;
    short8 af[4], bfv[4];
    #pragma unroll
    for (int mi=0;mi<4;mi++){
      int r = wm*64 + mi*16 + (lane & 15);
      int idx = r*32 + kofs;
      int sw = idx ^ (((idx >> 6) & 7) << 3);
      af[mi] = *reinterpret_cast<const short8*>(&As[cur][sw]);
    }
    #pragma unroll
    for (int ni=0;ni<4;ni++){
      int r = wn*64 + ni*16 + (lane & 15);
      int idx = r*32 + kofs;
      int sw = idx ^ (((idx >> 6) & 7) << 3);
      bfv[ni] = *reinterpret_cast<const short8*>(&Bs[cur][sw]);
    }
    #pragma unroll
    for (int mi=0;mi<4;mi++)
      #pragma unroll
      for (int ni=0;ni<4;ni++)
        acc[mi][ni] = __builtin_amdgcn_mfma_f32_16x16x32_bf16(af[mi], bfv[ni], acc[mi][ni], 0, 0, 0);
    __builtin_amdgcn_s_barrier();
    cur ^= 1;
  }

  const int crow = row0 + wm*64;
  const int ccol = col0 + wn*64 + (lane & 15);
  #pragma unroll
  for (int mi=0;mi<4;mi++){
    #pragma unroll
    for (int j=0;j<4;j++){
      int gr = crow + mi*16 + (lane >> 4)*4 + j;
      if (gr < nrows){
        #pragma unroll
        for (int ni=0;ni<4;ni++){
          float v = acc[mi][ni][j];
          int gc = ccol + ni*16;
          if (EMB){
            v = fmaxf(v + bias[gc], 0.f);
            outp[(size_t)gr*HDIM + gc] = f2bf(v);
          } else {
            outp[((size_t)(gc >> 5)*N_NODES + gr)*32 + (gc & 31)] = f2bf(v);
          }
        }
      }
    }
  }
}

// ---------------- channel-sliced aggregation v2: 1 node/wave/slice, 16-edge-parallel ----------------
// blockIdx.x & 7 = slice (round-robin block->XCD pins slice to XCD; 3.2MB slice fits 4MB L2).
// lane = edge_sub*4 + ch_sub; quad of lanes shares an edge, each lane gathers 16B (8 ch).
__global__ __launch_bounds__(256) void k_agg(const unsigned short* __restrict__ mt_all,
                                             const int* __restrict__ rowp,
                                             const int2* __restrict__ csr,
                                             const float* __restrict__ S, const float* __restrict__ T,
                                             unsigned short* __restrict__ h){
  const int slice = blockIdx.x & (NSLICE-1);
  const int node = (blockIdx.x >> 3)*4 + (threadIdx.x >> 6);
  if (node >= N_NODES) return;
  const int lane = threadIdx.x & 63;
  const int csub = lane & 3;          // which 8-ch group of the 32-ch slice
  const int esub = lane >> 2;         // 0..15 edge sub-lane

  const unsigned short* __restrict__ mt = mt_all + (size_t)slice*N_NODES*32;

  int s = rowp[node], e = rowp[node+1];
  float dn = rsqrtf(1.0f + (float)(e - s));

  float acc[8];
  #pragma unroll
  for (int j=0;j<8;j++) acc[j] = 0.f;

  int i = s + esub;
  // 2-deep unroll: 32 edges in flight per wave
  for (; i + 16 < e; i += 32){
    int2 e0 = csr[i], e1 = csr[i+16];
    float w0 = __int_as_float(e0.y), w1 = __int_as_float(e1.y);
    u16x8 m0 = *reinterpret_cast<const u16x8*>(mt + (size_t)e0.x*32 + csub*8);
    u16x8 m1 = *reinterpret_cast<const u16x8*>(mt + (size_t)e1.x*32 + csub*8);
    #pragma unroll
    for (int j=0;j<8;j++) acc[j] += w0*bf2f(m0[j]) + w1*bf2f(m1[j]);
  }
  if (i < e){
    int2 e0 = csr[i];
    float w0 = __int_as_float(e0.y);
    u16x8 m0 = *reinterpret_cast<const u16x8*>(mt + (size_t)e0.x*32 + csub*8);
    #pragma unroll
    for (int j=0;j<8;j++) acc[j] += w0*bf2f(m0[j]);
  }

  // reduce across the 16 edge sub-lanes (lane bits 2..5)
  #pragma unroll
  for (int off=4; off<64; off<<=1)
    #pragma unroll
    for (int j=0;j<8;j++) acc[j] += __shfl_xor(acc[j], off);

  if (esub == 0){
    const int c = slice*32 + csub*8;
    const size_t base = (size_t)node*HDIM + c;
    u16x8 ms = *reinterpret_cast<const u16x8*>(mt + (size_t)node*32 + csub*8);
    float4 S0 = ld4(S + c), S1 = ld4(S + c + 4);
    float4 T0 = ld4(T + c), T1 = ld4(T + c + 4);
    u16x8 hold = *reinterpret_cast<const u16x8*>(h + base);
    float Sv[8] = {S0.x,S0.y,S0.z,S0.w,S1.x,S1.y,S1.z,S1.w};
    float Tv[8] = {T0.x,T0.y,T0.z,T0.w,T1.x,T1.y,T1.z,T1.w};
    u16x8 ob;
    #pragma unroll
    for (int j=0;j<8;j++){
      float a = acc[j] + bf2f(ms[j]) * dn;      // self term
      float o = fmaxf(a*dn*Sv[j] + Tv[j], 0.f) + bf2f(hold[j]);
      ob[j] = f2bf(o);
    }
    *reinterpret_cast<u16x8*>(h + base) = ob;
  }
}

// ---------------- global mean pool (batch_idx sorted), bf16 h ----------------
__device__ __forceinline__ int lbound(const int* __restrict__ a, int n, int key){
  int lo = 0, hi = n;
  while (lo < hi){ int mid = (lo + hi) >> 1; if (a[mid] < key) lo = mid + 1; else hi = mid; }
  return lo;
}

__global__ __launch_bounds__(128) void k_pool(const unsigned short* __restrict__ h, const int* __restrict__ batch,
                                              float* __restrict__ g){
  int gi = blockIdx.x;
  int lo = lbound(batch, N_NODES, gi);
  int hi = lbound(batch, N_NODES, gi + 1);
  int t = threadIdx.x;
  float s0 = 0.f, s1 = 0.f;
  for (int n = lo; n < hi; ++n){
    unsigned u = *reinterpret_cast<const unsigned*>(h + (size_t)n*HDIM + 2*t);
    s0 += bf2f((unsigned short)(u & 0xffffu));
    s1 += bf2f((unsigned short)(u >> 16));
  }
  float inv = 1.0f / fmaxf((float)(hi - lo), 1.0f);
  g[(size_t)gi*HDIM + 2*t]     = s0 * inv;
  g[(size_t)gi*HDIM + 2*t + 1] = s1 * inv;
}

// ---------------- fused 3-layer property heads, GB graphs per block ----------------
__global__ __launch_bounds__(128) void k_heads(const float* __restrict__ g,
                                               const float* __restrict__ W1, const float* __restrict__ b1,
                                               const float* __restrict__ W2, const float* __restrict__ b2,
                                               const float* __restrict__ W3, const float* __restrict__ b3,
                                               float* __restrict__ out){
  int g0 = blockIdx.x * GB, p = blockIdx.y;
  __shared__ float gs[GB][HDIM];
  __shared__ float z1[GB][128];
  int t = threadIdx.x;
  #pragma unroll
  for (int gi=0; gi<GB; gi++){
    gs[gi][t]       = g[(size_t)(g0+gi)*HDIM + t];
    gs[gi][t + 128] = g[(size_t)(g0+gi)*HDIM + t + 128];
  }
  __syncthreads();

  const float* w1 = W1 + (size_t)p*HDIM*128;
  float a[GB];
  #pragma unroll
  for (int gi=0; gi<GB; gi++) a[gi] = 0.f;
  for (int i=0;i<HDIM;i++){
    float wv = w1[(size_t)i*128 + t];
    #pragma unroll
    for (int gi=0; gi<GB; gi++) a[gi] += gs[gi][i] * wv;
  }
  float b1v = b1[p*128 + t];
  #pragma unroll
  for (int gi=0; gi<GB; gi++) z1[gi][t] = fmaxf(a[gi] + b1v, 0.f);
  __syncthreads();

  if (t < 64){
    const float* w2 = W2 + (size_t)p*128*64;
    float a2[GB];
    #pragma unroll
    for (int gi=0; gi<GB; gi++) a2[gi] = 0.f;
    for (int i=0;i<128;i++){
      float wv = w2[(size_t)i*64 + t];
      #pragma unroll
      for (int gi=0; gi<GB; gi++) a2[gi] += z1[gi][i] * wv;
    }
    float w3v = W3[p*64 + t];
    float b2v = b2[p*64 + t];
    float b3v = b3[p];
    #pragma unroll
    for (int gi=0; gi<GB; gi++){
      float z2 = fmaxf(a2[gi] + b2v, 0.f);
      float v = z2 * w3v;
      #pragma unroll
      for (int off=32; off>0; off>>=1) v += __shfl_down(v, off, 64);
      if (t == 0) out[(size_t)(g0+gi)*NPROPS + p] = v + b3v;
    }
  }
}

// ---------------- launch ----------------
extern "C" void kernel_launch(void* const* d_in, const int* in_sizes, int n_in,
                              void* d_out, int out_size, void* d_ws, size_t ws_size,
                              hipStream_t stream){
  const float* x     = (const float*)d_in[0];
  const int*   ei    = (const int*)  d_in[1];
  const int*   batch = (const int*)  d_in[2];
  const float* embW  = (const float*)d_in[3];
  const float* embb  = (const float*)d_in[4];
  const float* gcnW  = (const float*)d_in[5];
  const float* gcnb  = (const float*)d_in[6];
  const float* bng   = (const float*)d_in[7];
  const float* bnb   = (const float*)d_in[8];
  const float* bnm   = (const float*)d_in[9];
  const float* bnv   = (const float*)d_in[10];
  const float* h1W   = (const float*)d_in[11];
  const float* h1b   = (const float*)d_in[12];
  const float* h2W   = (const float*)d_in[13];
  const float* h2b   = (const float*)d_in[14];
  const float* h3W   = (const float*)d_in[15];
  const float* h3b   = (const float*)d_in[16];
  float* out = (float*)d_out;

  char* w = (char*)d_ws;
  auto alloc = [&](size_t bytes)->char*{ char* p = w; w += (bytes + 255) & ~(size_t)255; return p; };
  unsigned short* h    = (unsigned short*)alloc((size_t)N_NODES*HDIM*2);   // bf16 h
  unsigned short* m    = (unsigned short*)alloc((size_t)N_NODES*HDIM*2);   // tiled m_t[8][N][32]; reused as xb
  int*   cnt  = (int*)  alloc((size_t)N_NODES*4);
  int*   fill = (int*)  alloc((size_t)N_NODES*4);
  int*   rowp = (int*)  alloc((size_t)(N_NODES+1)*4);
  float* dinv = (float*)alloc((size_t)N_NODES*4);
  int2*  csr  = (int2*) alloc((size_t)N_EDGES*8);
  int*   part = (int*)  alloc(1024);
  float* gp   = (float*)alloc((size_t)N_GRAPHS*HDIM*4);
  unsigned short* embWt = (unsigned short*)alloc((size_t)NODE_DIMC*HDIM*2);
  unsigned short* gcnWt = (unsigned short*)alloc((size_t)NLAYERS*HDIM*HDIM*2);
  float* bnS  = (float*)alloc((size_t)NLAYERS*HDIM*4);
  float* bnT  = (float*)alloc((size_t)NLAYERS*HDIM*4);

  hipMemsetAsync(cnt, 0, (size_t)N_NODES*4, stream);

  const int EB = (N_EDGES + 255)/256;
  k_count<<<EB,256,0,stream>>>(ei, cnt);
  k_scan1<<<NBLK,256,0,stream>>>(cnt, rowp, part);
  k_scan2<<<1,256,0,stream>>>(part);
  k_scan3<<<NBLK,256,0,stream>>>(cnt, rowp, part, dinv, fill);
  k_fill<<<EB,256,0,stream>>>(ei, rowp, fill, dinv, csr);

  unsigned short* xb = m;
  k_prep<<<(PREP_TOTAL + 255)/256,256,0,stream>>>(x, xb, embW, embWt, gcnW, gcnWt,
                                                  gcnb, bng, bnb, bnm, bnv, bnS, bnT);

  const int RB = (N_NODES + 127)/128;
  k_mgemm<NODE_DIMC, true><<<dim3(RB,2),256,0,stream>>>(xb, embWt, embb, h, N_NODES);

  const int AB = ((N_NODES + 3)/4) * NSLICE;   // 4 nodes/block x 8 slices
  for (int l = 0; l < NLAYERS; ++l){
    k_mgemm<HDIM, false><<<dim3(RB,2),256,0,stream>>>(h, gcnWt + (size_t)l*HDIM*HDIM, nullptr, m, N_NODES);
    k_agg<<<AB,256,0,stream>>>(m, rowp, csr, bnS + l*HDIM, bnT + l*HDIM, h);
  }

  k_pool<<<N_GRAPHS,128,0,stream>>>(h, batch, gp);
  k_heads<<<dim3((N_GRAPHS+GB-1)/GB,NPROPS),128,0,stream>>>(gp, h1W, h1b, h2W, h2b, h3W, h3b, out);
}

// Round 10
// 474.759 us; speedup vs baseline: 1.8413x; 1.8413x over previous
//
#include <hip/hip_runtime.h>

#define N_NODES 50000
#define N_EDGES 800000
#define N_GRAPHS 1000
#define NODE_DIMC 128
#define HDIM 256
#define NLAYERS 4
#define NPROPS 3
#define BN_EPSF 1e-5f
#define NBLK 196   // ceil(N_NODES/256)
#define GB 8       // graphs per head-block

typedef __attribute__((ext_vector_type(4))) float f32x4;
typedef __attribute__((ext_vector_type(8))) short short8;
typedef __attribute__((ext_vector_type(8))) unsigned short u16x8;

__device__ __forceinline__ float4 ld4(const float* p){ return *reinterpret_cast<const float4*>(p); }
__device__ __forceinline__ unsigned short f2bf(float f){
  unsigned u = __float_as_uint(f);
  return (unsigned short)((u + 0x7FFFu + ((u >> 16) & 1u)) >> 16);
}
__device__ __forceinline__ float bf2f(unsigned short s){ return __uint_as_float(((unsigned)s) << 16); }

__device__ __forceinline__ void gl2lds16(const void* g, void* l){
  __builtin_amdgcn_global_load_lds((const __attribute__((address_space(1))) unsigned int*)g,
                                   (__attribute__((address_space(3))) unsigned int*)l, 16, 0, 0);
}

// ---------------- CSR build ----------------
__global__ void k_count(const int* __restrict__ ei, int* __restrict__ cnt){
  int e = blockIdx.x*256 + threadIdx.x;
  if (e < N_EDGES) atomicAdd(&cnt[ei[N_EDGES + e]], 1);
}

__global__ void k_scan1(const int* __restrict__ cnt, int* __restrict__ rowp, int* __restrict__ part){
  __shared__ int s[256];
  int t = threadIdx.x;
  int i = blockIdx.x*256 + t;
  int v = (i < N_NODES) ? cnt[i] : 0;
  s[t] = v;
  __syncthreads();
  #pragma unroll
  for (int off=1; off<256; off<<=1){
    int x = s[t];
    int y = (t >= off) ? s[t-off] : 0;
    __syncthreads();
    s[t] = x + y;
    __syncthreads();
  }
  if (i < N_NODES) rowp[i+1] = s[t];
  if (t == 255) part[blockIdx.x] = s[255];
}

__global__ void k_scan2(int* __restrict__ part){
  __shared__ int s[256];
  int t = threadIdx.x;
  int v = (t < NBLK) ? part[t] : 0;
  s[t] = v;
  __syncthreads();
  #pragma unroll
  for (int off=1; off<256; off<<=1){
    int x = s[t];
    int y = (t >= off) ? s[t-off] : 0;
    __syncthreads();
    s[t] = x + y;
    __syncthreads();
  }
  if (t < NBLK) part[t] = s[t] - v;   // exclusive offsets
}

__global__ void k_scan3(const int* __restrict__ cnt, int* __restrict__ rowp,
                        const int* __restrict__ part, float* __restrict__ dinv,
                        int* __restrict__ fill){
  int i = blockIdx.x*256 + threadIdx.x;
  if (i < N_NODES){
    rowp[i+1] += part[blockIdx.x];
    dinv[i] = rsqrtf(1.0f + (float)cnt[i]);
    fill[i] = 0;
  }
  if (i == 0) rowp[0] = 0;
}

__global__ void k_fill(const int* __restrict__ ei, const int* __restrict__ rowp, int* __restrict__ fill,
                       const float* __restrict__ dinv, int2* __restrict__ csr){
  int e = blockIdx.x*256 + threadIdx.x;
  if (e >= N_EDGES) return;
  int sr = ei[e];
  int ds = ei[N_EDGES + e];
  int pos = rowp[ds] + atomicAdd(&fill[ds], 1);
  csr[pos] = make_int2(sr, __float_as_int(dinv[sr]));
}

// ---------------- fused prep: x->bf16, embWt, gcnWt, BN fold ----------------
#define XCVT_N (N_NODES*NODE_DIMC/4)
#define EMBWT_N (NODE_DIMC*HDIM)
#define GCNWT_N (NLAYERS*HDIM*HDIM)
#define BN_N (NLAYERS*HDIM)
#define PREP_TOTAL (XCVT_N + EMBWT_N + GCNWT_N + BN_N)

__global__ void k_prep(const float* __restrict__ x, unsigned short* __restrict__ xb,
                       const float* __restrict__ embW, unsigned short* __restrict__ embWt,
                       const float* __restrict__ gcnW, unsigned short* __restrict__ gcnWt,
                       const float* __restrict__ gcnb, const float* __restrict__ bng,
                       const float* __restrict__ bnb, const float* __restrict__ bnm,
                       const float* __restrict__ bnv, float* __restrict__ S, float* __restrict__ T){
  int idx = blockIdx.x*256 + threadIdx.x;
  if (idx < XCVT_N){
    float4 v = ld4(x + (size_t)idx*4);
    ushort4 o;
    o.x = f2bf(v.x); o.y = f2bf(v.y); o.z = f2bf(v.z); o.w = f2bf(v.w);
    *reinterpret_cast<ushort4*>(xb + (size_t)idx*4) = o;
    return;
  }
  idx -= XCVT_N;
  if (idx < EMBWT_N){
    int c = idx >> 7, k = idx & 127;
    embWt[idx] = f2bf(embW[(size_t)k*HDIM + c]);
    return;
  }
  idx -= EMBWT_N;
  if (idx < GCNWT_N){
    int l = idx >> 16, rem = idx & 65535;
    int c = rem >> 8, k = rem & 255;
    gcnWt[idx] = f2bf(gcnW[(size_t)l*HDIM*HDIM + (size_t)k*HDIM + c]);
    return;
  }
  idx -= GCNWT_N;
  if (idx < BN_N){
    float s = bng[idx] * rsqrtf(bnv[idx] + BN_EPSF);
    S[idx] = s;
    T[idx] = (gcnb[idx] - bnm[idx]) * s + bnb[idx];
  }
}

// ---------------- bf16 MFMA GEMM: 128x128 tile, BK=32, dbuf LDS + LDS-repacked epilogue ----------------
// SMEM union: K-loop uses As(2x8KB)+Bs(2x8KB)=32KB; epilogue reuses it as CT[128][136] bf16 (34.8KB).
template<int K, bool EMB>
__global__ __launch_bounds__(256) void k_mgemm(const unsigned short* __restrict__ A,
                                               const unsigned short* __restrict__ Wt,
                                               const float* __restrict__ bias,
                                               unsigned short* __restrict__ outp,
                                               int nrows){
  __shared__ unsigned short SMEM[17408];   // 34,816 B
  unsigned short* As0 = SMEM;              // As[buf] = SMEM + buf*4096
  unsigned short* Bs0 = SMEM + 8192;       // Bs[buf] = SMEM + 8192 + buf*4096
  const int t = threadIdx.x;
  const int lane = t & 63;
  const int wid = t >> 6;
  const int wm = wid >> 1, wn = wid & 1;
  const int row0 = blockIdx.x * 128;
  const int col0 = blockIdx.y * 128;
  constexpr int NK = K / 32;

  f32x4 acc[4][4];
  #pragma unroll
  for (int i=0;i<4;i++)
    #pragma unroll
    for (int j=0;j<4;j++) acc[i][j] = (f32x4){0.f,0.f,0.f,0.f};

  auto stage = [&](int buf, int k0){
    #pragma unroll
    for (int i=0;i<2;i++){
      int c0 = (wid*2 + i)*64;                  // wave-uniform chunk base (16B units)
      int c  = c0 + lane;
      int cs = c ^ ((c >> 3) & 7);              // pre-swizzled source chunk
      int r  = cs >> 2;
      int kp = (cs & 3) * 8;
      gl2lds16(A + (size_t)(row0 + r)*K + k0 + kp, As0 + buf*4096 + c0*8);
    }
    #pragma unroll
    for (int i=0;i<2;i++){
      int c0 = (wid*2 + i)*64;
      int c  = c0 + lane;
      int cs = c ^ ((c >> 3) & 7);
      int r  = cs >> 2;
      int kp = (cs & 3) * 8;
      gl2lds16(Wt + (size_t)(col0 + r)*K + k0 + kp, Bs0 + buf*4096 + c0*8);
    }
  };

  stage(0, 0);
  int cur = 0;
  #pragma unroll
  for (int tk = 0; tk < NK; ++tk){
    if (tk + 1 < NK){
      stage(cur ^ 1, (tk+1)*32);
      asm volatile("s_waitcnt vmcnt(4)" ::: "memory");
    } else {
      asm volatile("s_waitcnt vmcnt(0)" ::: "memory");
    }
    __builtin_amdgcn_s_barrier();
    const int kofs = (lane >> 4) * 8;
    short8 af[4], bfv[4];
    #pragma unroll
    for (int mi=0;mi<4;mi++){
      int r = wm*64 + mi*16 + (lane & 15);
      int idx = r*32 + kofs;
      int sw = idx ^ (((idx >> 6) & 7) << 3);
      af[mi] = *reinterpret_cast<const short8*>(As0 + cur*4096 + sw);
    }
    #pragma unroll
    for (int ni=0;ni<4;ni++){
      int r = wn*64 + ni*16 + (lane & 15);
      int idx = r*32 + kofs;
      int sw = idx ^ (((idx >> 6) & 7) << 3);
      bfv[ni] = *reinterpret_cast<const short8*>(Bs0 + cur*4096 + sw);
    }
    #pragma unroll
    for (int mi=0;mi<4;mi++)
      #pragma unroll
      for (int ni=0;ni<4;ni++)
        acc[mi][ni] = __builtin_amdgcn_mfma_f32_16x16x32_bf16(af[mi], bfv[ni], acc[mi][ni], 0, 0, 0);
    __builtin_amdgcn_s_barrier();
    cur ^= 1;
  }

  // ---- epilogue: acc -> CT (bf16, padded stride 136) -> coalesced u16x8 stores ----
  __syncthreads();                            // all waves done with As/Bs
  unsigned short* CT = SMEM;
  const int rl0 = wm*64;
  const int cl0 = wn*64 + (lane & 15);
  #pragma unroll
  for (int mi=0;mi<4;mi++){
    #pragma unroll
    for (int j=0;j<4;j++){
      int rl = rl0 + mi*16 + (lane >> 4)*4 + j;
      #pragma unroll
      for (int ni=0;ni<4;ni++){
        float v = acc[mi][ni][j];
        int cl = cl0 + ni*16;
        if (EMB) v = fmaxf(v + bias[col0 + cl], 0.f);
        CT[rl*136 + cl] = f2bf(v);
      }
    }
  }
  __syncthreads();
  #pragma unroll
  for (int it=0; it<8; ++it){
    int cidx = t + it*256;          // 0..2047
    int rl = cidx >> 4;
    int ck = cidx & 15;
    int gr = row0 + rl;
    if (gr < nrows){
      u16x8 v = *reinterpret_cast<const u16x8*>(CT + rl*136 + ck*8);
      *reinterpret_cast<u16x8*>(outp + (size_t)gr*HDIM + col0 + ck*8) = v;
    }
  }
}

// ---------------- fused aggregation: half-wave edge split, 4-deep, bf16 h (R8 version) ----------------
__global__ __launch_bounds__(256) void k_agg(const unsigned short* __restrict__ m, const int* __restrict__ rowp,
                                             const int2* __restrict__ csr,
                                             const float* __restrict__ S, const float* __restrict__ T,
                                             unsigned short* __restrict__ h){
  int node = blockIdx.x*4 + (threadIdx.x >> 6);
  int lane = threadIdx.x & 63;
  int half = lane >> 5;
  int c = (lane & 31) * 8;

  int s = rowp[node], e = rowp[node+1];
  float dn = rsqrtf(1.0f + (float)(e - s));   // deg = 1 + in-degree

  float acc[8];
  const size_t base = (size_t)node*HDIM + c;
  if (half == 0){
    u16x8 ms = *reinterpret_cast<const u16x8*>(m + base);
    #pragma unroll
    for (int j=0;j<8;j++) acc[j] = bf2f(ms[j]) * dn;
  } else {
    #pragma unroll
    for (int j=0;j<8;j++) acc[j] = 0.f;
  }

  int i = s + half;
  for (; i + 6 < e; i += 8){
    int2 e0 = csr[i], e1 = csr[i+2], e2 = csr[i+4], e3 = csr[i+6];
    float w0 = __int_as_float(e0.y), w1 = __int_as_float(e1.y);
    float w2 = __int_as_float(e2.y), w3 = __int_as_float(e3.y);
    u16x8 m0 = *reinterpret_cast<const u16x8*>(m + (size_t)e0.x*HDIM + c);
    u16x8 m1 = *reinterpret_cast<const u16x8*>(m + (size_t)e1.x*HDIM + c);
    u16x8 m2 = *reinterpret_cast<const u16x8*>(m + (size_t)e2.x*HDIM + c);
    u16x8 m3 = *reinterpret_cast<const u16x8*>(m + (size_t)e3.x*HDIM + c);
    #pragma unroll
    for (int j=0;j<8;j++){
      acc[j] += w0*bf2f(m0[j]) + w1*bf2f(m1[j]);
      acc[j] += w2*bf2f(m2[j]) + w3*bf2f(m3[j]);
    }
  }
  if (i + 2 < e){
    int2 e0 = csr[i], e1 = csr[i+2];
    float w0 = __int_as_float(e0.y), w1 = __int_as_float(e1.y);
    u16x8 m0 = *reinterpret_cast<const u16x8*>(m + (size_t)e0.x*HDIM + c);
    u16x8 m1 = *reinterpret_cast<const u16x8*>(m + (size_t)e1.x*HDIM + c);
    #pragma unroll
    for (int j=0;j<8;j++) acc[j] += w0*bf2f(m0[j]) + w1*bf2f(m1[j]);
    i += 4;
  }
  if (i < e){
    int2 e0 = csr[i];
    float w0 = __int_as_float(e0.y);
    u16x8 m0 = *reinterpret_cast<const u16x8*>(m + (size_t)e0.x*HDIM + c);
    #pragma unroll
    for (int j=0;j<8;j++) acc[j] += w0*bf2f(m0[j]);
  }

  #pragma unroll
  for (int j=0;j<8;j++) acc[j] += __shfl_xor(acc[j], 32);

  if (half == 0){
    float4 S0 = ld4(S + c), S1 = ld4(S + c + 4);
    float4 T0 = ld4(T + c), T1 = ld4(T + c + 4);
    u16x8 hold = *reinterpret_cast<const u16x8*>(h + base);
    float Sv[8] = {S0.x,S0.y,S0.z,S0.w,S1.x,S1.y,S1.z,S1.w};
    float Tv[8] = {T0.x,T0.y,T0.z,T0.w,T1.x,T1.y,T1.z,T1.w};
    u16x8 ob;
    #pragma unroll
    for (int j=0;j<8;j++){
      float o = fmaxf(acc[j]*dn*Sv[j] + Tv[j], 0.f) + bf2f(hold[j]);
      ob[j] = f2bf(o);
    }
    *reinterpret_cast<u16x8*>(h + base) = ob;
  }
}

// ---------------- global mean pool (batch_idx sorted), bf16 h ----------------
__device__ __forceinline__ int lbound(const int* __restrict__ a, int n, int key){
  int lo = 0, hi = n;
  while (lo < hi){ int mid = (lo + hi) >> 1; if (a[mid] < key) lo = mid + 1; else hi = mid; }
  return lo;
}

__global__ __launch_bounds__(128) void k_pool(const unsigned short* __restrict__ h, const int* __restrict__ batch,
                                              float* __restrict__ g){
  int gi = blockIdx.x;
  int lo = lbound(batch, N_NODES, gi);
  int hi = lbound(batch, N_NODES, gi + 1);
  int t = threadIdx.x;
  float s0 = 0.f, s1 = 0.f;
  for (int n = lo; n < hi; ++n){
    unsigned u = *reinterpret_cast<const unsigned*>(h + (size_t)n*HDIM + 2*t);
    s0 += bf2f((unsigned short)(u & 0xffffu));
    s1 += bf2f((unsigned short)(u >> 16));
  }
  float inv = 1.0f / fmaxf((float)(hi - lo), 1.0f);
  g[(size_t)gi*HDIM + 2*t]     = s0 * inv;
  g[(size_t)gi*HDIM + 2*t + 1] = s1 * inv;
}

// ---------------- fused 3-layer property heads, GB graphs per block ----------------
__global__ __launch_bounds__(128) void k_heads(const float* __restrict__ g,
                                               const float* __restrict__ W1, const float* __restrict__ b1,
                                               const float* __restrict__ W2, const float* __restrict__ b2,
                                               const float* __restrict__ W3, const float* __restrict__ b3,
                                               float* __restrict__ out){
  int g0 = blockIdx.x * GB, p = blockIdx.y;
  __shared__ float gs[GB][HDIM];
  __shared__ float z1[GB][128];
  int t = threadIdx.x;
  #pragma unroll
  for (int gi=0; gi<GB; gi++){
    gs[gi][t]       = g[(size_t)(g0+gi)*HDIM + t];
    gs[gi][t + 128] = g[(size_t)(g0+gi)*HDIM + t + 128];
  }
  __syncthreads();

  const float* w1 = W1 + (size_t)p*HDIM*128;
  float a[GB];
  #pragma unroll
  for (int gi=0; gi<GB; gi++) a[gi] = 0.f;
  for (int i=0;i<HDIM;i++){
    float wv = w1[(size_t)i*128 + t];
    #pragma unroll
    for (int gi=0; gi<GB; gi++) a[gi] += gs[gi][i] * wv;
  }
  float b1v = b1[p*128 + t];
  #pragma unroll
  for (int gi=0; gi<GB; gi++) z1[gi][t] = fmaxf(a[gi] + b1v, 0.f);
  __syncthreads();

  if (t < 64){
    const float* w2 = W2 + (size_t)p*128*64;
    float a2[GB];
    #pragma unroll
    for (int gi=0; gi<GB; gi++) a2[gi] = 0.f;
    for (int i=0;i<128;i++){
      float wv = w2[(size_t)i*64 + t];
      #pragma unroll
      for (int gi=0; gi<GB; gi++) a2[gi] += z1[gi][i] * wv;
    }
    float w3v = W3[p*64 + t];
    float b2v = b2[p*64 + t];
    float b3v = b3[p];
    #pragma unroll
    for (int gi=0; gi<GB; gi++){
      float z2 = fmaxf(a2[gi] + b2v, 0.f);
      float v = z2 * w3v;
      #pragma unroll
      for (int off=32; off>0; off>>=1) v += __shfl_down(v, off, 64);
      if (t == 0) out[(size_t)(g0+gi)*NPROPS + p] = v + b3v;
    }
  }
}

// ---------------- launch ----------------
extern "C" void kernel_launch(void* const* d_in, const int* in_sizes, int n_in,
                              void* d_out, int out_size, void* d_ws, size_t ws_size,
                              hipStream_t stream){
  const float* x     = (const float*)d_in[0];
  const int*   ei    = (const int*)  d_in[1];
  const int*   batch = (const int*)  d_in[2];
  const float* embW  = (const float*)d_in[3];
  const float* embb  = (const float*)d_in[4];
  const float* gcnW  = (const float*)d_in[5];
  const float* gcnb  = (const float*)d_in[6];
  const float* bng   = (const float*)d_in[7];
  const float* bnb   = (const float*)d_in[8];
  const float* bnm   = (const float*)d_in[9];
  const float* bnv   = (const float*)d_in[10];
  const float* h1W   = (const float*)d_in[11];
  const float* h1b   = (const float*)d_in[12];
  const float* h2W   = (const float*)d_in[13];
  const float* h2b   = (const float*)d_in[14];
  const float* h3W   = (const float*)d_in[15];
  const float* h3b   = (const float*)d_in[16];
  float* out = (float*)d_out;

  char* w = (char*)d_ws;
  auto alloc = [&](size_t bytes)->char*{ char* p = w; w += (bytes + 255) & ~(size_t)255; return p; };
  unsigned short* h    = (unsigned short*)alloc((size_t)N_NODES*HDIM*2);   // bf16 h
  unsigned short* m    = (unsigned short*)alloc((size_t)N_NODES*HDIM*2);   // bf16 messages; reused as xb
  int*   cnt  = (int*)  alloc((size_t)N_NODES*4);
  int*   fill = (int*)  alloc((size_t)N_NODES*4);
  int*   rowp = (int*)  alloc((size_t)(N_NODES+1)*4);
  float* dinv = (float*)alloc((size_t)N_NODES*4);
  int2*  csr  = (int2*) alloc((size_t)N_EDGES*8);
  int*   part = (int*)  alloc(1024);
  float* gp   = (float*)alloc((size_t)N_GRAPHS*HDIM*4);
  unsigned short* embWt = (unsigned short*)alloc((size_t)NODE_DIMC*HDIM*2);
  unsigned short* gcnWt = (unsigned short*)alloc((size_t)NLAYERS*HDIM*HDIM*2);
  float* bnS  = (float*)alloc((size_t)NLAYERS*HDIM*4);
  float* bnT  = (float*)alloc((size_t)NLAYERS*HDIM*4);

  hipMemsetAsync(cnt, 0, (size_t)N_NODES*4, stream);

  const int EB = (N_EDGES + 255)/256;
  k_count<<<EB,256,0,stream>>>(ei, cnt);
  k_scan1<<<NBLK,256,0,stream>>>(cnt, rowp, part);
  k_scan2<<<1,256,0,stream>>>(part);
  k_scan3<<<NBLK,256,0,stream>>>(cnt, rowp, part, dinv, fill);
  k_fill<<<EB,256,0,stream>>>(ei, rowp, fill, dinv, csr);

  unsigned short* xb = m;
  k_prep<<<(PREP_TOTAL + 255)/256,256,0,stream>>>(x, xb, embW, embWt, gcnW, gcnWt,
                                                  gcnb, bng, bnb, bnm, bnv, bnS, bnT);

  const int RB = (N_NODES + 127)/128;
  k_mgemm<NODE_DIMC, true><<<dim3(RB,2),256,0,stream>>>(xb, embWt, embb, h, N_NODES);

  for (int l = 0; l < NLAYERS; ++l){
    k_mgemm<HDIM, false><<<dim3(RB,2),256,0,stream>>>(h, gcnWt + (size_t)l*HDIM*HDIM, nullptr, m, N_NODES);
    k_agg<<<(N_NODES+3)/4,256,0,stream>>>(m, rowp, csr, bnS + l*HDIM, bnT + l*HDIM, h);
  }

  k_pool<<<N_GRAPHS,128,0,stream>>>(h, batch, gp);
  k_heads<<<dim3((N_GRAPHS+GB-1)/GB,NPROPS),128,0,stream>>>(gp, h1W, h1b, h2W, h2b, h3W, h3b, out);
}

// Round 11
// 472.088 us; speedup vs baseline: 1.8518x; 1.0057x over previous
//
#include <hip/hip_runtime.h>

#define N_NODES 50000
#define N_EDGES 800000
#define N_GRAPHS 1000
#define NODE_DIMC 128
#define HDIM 256
#define NLAYERS 4
#define NPROPS 3
#define BN_EPSF 1e-5f
#define NBLK 196   // ceil(N_NODES/256)
#define GB 8       // graphs per head-block

typedef __attribute__((ext_vector_type(4))) float f32x4;
typedef __attribute__((ext_vector_type(8))) short short8;
typedef __attribute__((ext_vector_type(8))) unsigned short u16x8;

__device__ __forceinline__ float4 ld4(const float* p){ return *reinterpret_cast<const float4*>(p); }
__device__ __forceinline__ unsigned short f2bf(float f){
  unsigned u = __float_as_uint(f);
  return (unsigned short)((u + 0x7FFFu + ((u >> 16) & 1u)) >> 16);
}
__device__ __forceinline__ float bf2f(unsigned short s){ return __uint_as_float(((unsigned)s) << 16); }

__device__ __forceinline__ void gl2lds16(const void* g, void* l){
  __builtin_amdgcn_global_load_lds((const __attribute__((address_space(1))) unsigned int*)g,
                                   (__attribute__((address_space(3))) unsigned int*)l, 16, 0, 0);
}

// ---------------- CSR build ----------------
__global__ void k_count(const int* __restrict__ ei, int* __restrict__ cnt){
  int e = blockIdx.x*256 + threadIdx.x;
  if (e < N_EDGES) atomicAdd(&cnt[ei[N_EDGES + e]], 1);
}

__global__ void k_scan1(const int* __restrict__ cnt, int* __restrict__ rowp, int* __restrict__ part){
  __shared__ int s[256];
  int t = threadIdx.x;
  int i = blockIdx.x*256 + t;
  int v = (i < N_NODES) ? cnt[i] : 0;
  s[t] = v;
  __syncthreads();
  #pragma unroll
  for (int off=1; off<256; off<<=1){
    int x = s[t];
    int y = (t >= off) ? s[t-off] : 0;
    __syncthreads();
    s[t] = x + y;
    __syncthreads();
  }
  if (i < N_NODES) rowp[i+1] = s[t];
  if (t == 255) part[blockIdx.x] = s[255];
}

__global__ void k_scan2(int* __restrict__ part){
  __shared__ int s[256];
  int t = threadIdx.x;
  int v = (t < NBLK) ? part[t] : 0;
  s[t] = v;
  __syncthreads();
  #pragma unroll
  for (int off=1; off<256; off<<=1){
    int x = s[t];
    int y = (t >= off) ? s[t-off] : 0;
    __syncthreads();
    s[t] = x + y;
    __syncthreads();
  }
  if (t < NBLK) part[t] = s[t] - v;   // exclusive offsets
}

__global__ void k_scan3(const int* __restrict__ cnt, int* __restrict__ rowp,
                        const int* __restrict__ part, float* __restrict__ dinv,
                        int* __restrict__ fill){
  int i = blockIdx.x*256 + threadIdx.x;
  if (i < N_NODES){
    rowp[i+1] += part[blockIdx.x];
    dinv[i] = rsqrtf(1.0f + (float)cnt[i]);
    fill[i] = 0;
  }
  if (i == 0) rowp[0] = 0;
}

__global__ void k_fill(const int* __restrict__ ei, const int* __restrict__ rowp, int* __restrict__ fill,
                       const float* __restrict__ dinv, int2* __restrict__ csr){
  int e = blockIdx.x*256 + threadIdx.x;
  if (e >= N_EDGES) return;
  int sr = ei[e];
  int ds = ei[N_EDGES + e];
  int pos = rowp[ds] + atomicAdd(&fill[ds], 1);
  csr[pos] = make_int2(sr, __float_as_int(dinv[sr]));
}

// ---------------- fused prep: x->bf16, embWt, gcnWt, BN fold ----------------
#define XCVT_N (N_NODES*NODE_DIMC/4)
#define EMBWT_N (NODE_DIMC*HDIM)
#define GCNWT_N (NLAYERS*HDIM*HDIM)
#define BN_N (NLAYERS*HDIM)
#define PREP_TOTAL (XCVT_N + EMBWT_N + GCNWT_N + BN_N)

__global__ void k_prep(const float* __restrict__ x, unsigned short* __restrict__ xb,
                       const float* __restrict__ embW, unsigned short* __restrict__ embWt,
                       const float* __restrict__ gcnW, unsigned short* __restrict__ gcnWt,
                       const float* __restrict__ gcnb, const float* __restrict__ bng,
                       const float* __restrict__ bnb, const float* __restrict__ bnm,
                       const float* __restrict__ bnv, float* __restrict__ S, float* __restrict__ T){
  int idx = blockIdx.x*256 + threadIdx.x;
  if (idx < XCVT_N){
    float4 v = ld4(x + (size_t)idx*4);
    ushort4 o;
    o.x = f2bf(v.x); o.y = f2bf(v.y); o.z = f2bf(v.z); o.w = f2bf(v.w);
    *reinterpret_cast<ushort4*>(xb + (size_t)idx*4) = o;
    return;
  }
  idx -= XCVT_N;
  if (idx < EMBWT_N){
    int c = idx >> 7, k = idx & 127;
    embWt[idx] = f2bf(embW[(size_t)k*HDIM + c]);
    return;
  }
  idx -= EMBWT_N;
  if (idx < GCNWT_N){
    int l = idx >> 16, rem = idx & 65535;
    int c = rem >> 8, k = rem & 255;
    gcnWt[idx] = f2bf(gcnW[(size_t)l*HDIM*HDIM + (size_t)k*HDIM + c]);
    return;
  }
  idx -= GCNWT_N;
  if (idx < BN_N){
    float s = bng[idx] * rsqrtf(bnv[idx] + BN_EPSF);
    S[idx] = s;
    T[idx] = (gcnb[idx] - bnm[idx]) * s + bnb[idx];
  }
}

// ---------------- bf16 MFMA GEMM: BM=64 x BN=256 (full width, A read ONCE), BK=32, dbuf LDS ----------------
// LDS: A 2x4KB + B 2x16KB = 40KB; epilogue unions SMEM as CT[64][268] bf16 (33.5KB).
// 4 waves; wave w owns cols w*64..w*64+63, all 64 rows. acc[4][4] per wave.
template<int K, bool EMB>
__global__ __launch_bounds__(256) void k_mgemm(const unsigned short* __restrict__ A,
                                               const unsigned short* __restrict__ Wt,
                                               const float* __restrict__ bias,
                                               unsigned short* __restrict__ outp,
                                               int nrows){
  __shared__ unsigned short SMEM[20480];   // 40,960 B
  unsigned short* As0 = SMEM;              // As[buf] = SMEM + buf*2048 (64 rows x 32 k)
  unsigned short* Bs0 = SMEM + 4096;       // Bs[buf] = SMEM + 4096 + buf*8192 (256 cols x 32 k)
  const int t = threadIdx.x;
  const int lane = t & 63;
  const int wid = t >> 6;
  const int row0 = blockIdx.x * 64;
  constexpr int NK = K / 32;

  f32x4 acc[4][4];
  #pragma unroll
  for (int i=0;i<4;i++)
    #pragma unroll
    for (int j=0;j<4;j++) acc[i][j] = (f32x4){0.f,0.f,0.f,0.f};

  auto stage = [&](int buf, int k0){
    // A: 256 chunks of 16B, one per thread
    {
      int c0 = wid*64;                    // wave-uniform chunk base
      int c  = c0 + lane;
      int cs = c ^ ((c >> 3) & 7);        // involution on chunk index
      int r  = cs >> 2;                   // 4 chunks per 64B row
      int kp = (cs & 3) * 8;
      gl2lds16(A + (size_t)(row0 + r)*K + k0 + kp, As0 + buf*2048 + c0*8);
    }
    // B: 1024 chunks, 4 per thread
    #pragma unroll
    for (int i=0;i<4;i++){
      int c0 = (wid*4 + i)*64;
      int c  = c0 + lane;
      int cs = c ^ ((c >> 3) & 7);
      int col = cs >> 2;
      int kp  = (cs & 3) * 8;
      gl2lds16(Wt + (size_t)col*K + k0 + kp, Bs0 + buf*8192 + c0*8);
    }
  };

  stage(0, 0);
  int cur = 0;
  #pragma unroll
  for (int tk = 0; tk < NK; ++tk){
    if (tk + 1 < NK){
      stage(cur ^ 1, (tk+1)*32);
      asm volatile("s_waitcnt vmcnt(5)" ::: "memory");   // current buffer's 5 issues done; next's 5 in flight
    } else {
      asm volatile("s_waitcnt vmcnt(0)" ::: "memory");
    }
    __builtin_amdgcn_s_barrier();
    const int kofs = (lane >> 4) * 8;
    short8 af[4], bfv[4];
    #pragma unroll
    for (int mi=0;mi<4;mi++){
      int r = mi*16 + (lane & 15);
      int idx = r*32 + kofs;
      int sw = idx ^ (((idx >> 6) & 7) << 3);
      af[mi] = *reinterpret_cast<const short8*>(As0 + cur*2048 + sw);
    }
    #pragma unroll
    for (int ni=0;ni<4;ni++){
      int col = wid*64 + ni*16 + (lane & 15);
      int idx = col*32 + kofs;
      int sw = idx ^ (((idx >> 6) & 7) << 3);
      bfv[ni] = *reinterpret_cast<const short8*>(Bs0 + cur*8192 + sw);
    }
    #pragma unroll
    for (int mi=0;mi<4;mi++)
      #pragma unroll
      for (int ni=0;ni<4;ni++)
        acc[mi][ni] = __builtin_amdgcn_mfma_f32_16x16x32_bf16(af[mi], bfv[ni], acc[mi][ni], 0, 0, 0);
    __builtin_amdgcn_s_barrier();
    cur ^= 1;
  }

  // ---- epilogue: acc -> CT[64][268] bf16 -> coalesced u16x8 stores (full 256-wide rows) ----
  __syncthreads();
  unsigned short* CT = SMEM;
  #pragma unroll
  for (int mi=0;mi<4;mi++){
    #pragma unroll
    for (int j=0;j<4;j++){
      int rl = mi*16 + (lane >> 4)*4 + j;
      #pragma unroll
      for (int ni=0;ni<4;ni++){
        float v = acc[mi][ni][j];
        int cl = wid*64 + ni*16 + (lane & 15);
        if (EMB) v = fmaxf(v + bias[cl], 0.f);
        CT[rl*268 + cl] = f2bf(v);
      }
    }
  }
  __syncthreads();
  #pragma unroll
  for (int it=0; it<8; ++it){
    int cidx = t + it*256;          // 0..2047 u16x8 chunks (64 rows x 32 chunks)
    int rl = cidx >> 5;
    int ck = cidx & 31;
    int gr = row0 + rl;
    if (gr < nrows){
      u16x8 v = *reinterpret_cast<const u16x8*>(CT + rl*268 + ck*8);
      *reinterpret_cast<u16x8*>(outp + (size_t)gr*HDIM + ck*8) = v;
    }
  }
}

// ---------------- fused aggregation: half-wave edge split, 4-deep, bf16 h (R8 version) ----------------
__global__ __launch_bounds__(256) void k_agg(const unsigned short* __restrict__ m, const int* __restrict__ rowp,
                                             const int2* __restrict__ csr,
                                             const float* __restrict__ S, const float* __restrict__ T,
                                             unsigned short* __restrict__ h){
  int node = blockIdx.x*4 + (threadIdx.x >> 6);
  int lane = threadIdx.x & 63;
  int half = lane >> 5;
  int c = (lane & 31) * 8;

  int s = rowp[node], e = rowp[node+1];
  float dn = rsqrtf(1.0f + (float)(e - s));   // deg = 1 + in-degree

  float acc[8];
  const size_t base = (size_t)node*HDIM + c;
  if (half == 0){
    u16x8 ms = *reinterpret_cast<const u16x8*>(m + base);
    #pragma unroll
    for (int j=0;j<8;j++) acc[j] = bf2f(ms[j]) * dn;
  } else {
    #pragma unroll
    for (int j=0;j<8;j++) acc[j] = 0.f;
  }

  int i = s + half;
  for (; i + 6 < e; i += 8){
    int2 e0 = csr[i], e1 = csr[i+2], e2 = csr[i+4], e3 = csr[i+6];
    float w0 = __int_as_float(e0.y), w1 = __int_as_float(e1.y);
    float w2 = __int_as_float(e2.y), w3 = __int_as_float(e3.y);
    u16x8 m0 = *reinterpret_cast<const u16x8*>(m + (size_t)e0.x*HDIM + c);
    u16x8 m1 = *reinterpret_cast<const u16x8*>(m + (size_t)e1.x*HDIM + c);
    u16x8 m2 = *reinterpret_cast<const u16x8*>(m + (size_t)e2.x*HDIM + c);
    u16x8 m3 = *reinterpret_cast<const u16x8*>(m + (size_t)e3.x*HDIM + c);
    #pragma unroll
    for (int j=0;j<8;j++){
      acc[j] += w0*bf2f(m0[j]) + w1*bf2f(m1[j]);
      acc[j] += w2*bf2f(m2[j]) + w3*bf2f(m3[j]);
    }
  }
  if (i + 2 < e){
    int2 e0 = csr[i], e1 = csr[i+2];
    float w0 = __int_as_float(e0.y), w1 = __int_as_float(e1.y);
    u16x8 m0 = *reinterpret_cast<const u16x8*>(m + (size_t)e0.x*HDIM + c);
    u16x8 m1 = *reinterpret_cast<const u16x8*>(m + (size_t)e1.x*HDIM + c);
    #pragma unroll
    for (int j=0;j<8;j++) acc[j] += w0*bf2f(m0[j]) + w1*bf2f(m1[j]);
    i += 4;
  }
  if (i < e){
    int2 e0 = csr[i];
    float w0 = __int_as_float(e0.y);
    u16x8 m0 = *reinterpret_cast<const u16x8*>(m + (size_t)e0.x*HDIM + c);
    #pragma unroll
    for (int j=0;j<8;j++) acc[j] += w0*bf2f(m0[j]);
  }

  #pragma unroll
  for (int j=0;j<8;j++) acc[j] += __shfl_xor(acc[j], 32);

  if (half == 0){
    float4 S0 = ld4(S + c), S1 = ld4(S + c + 4);
    float4 T0 = ld4(T + c), T1 = ld4(T + c + 4);
    u16x8 hold = *reinterpret_cast<const u16x8*>(h + base);
    float Sv[8] = {S0.x,S0.y,S0.z,S0.w,S1.x,S1.y,S1.z,S1.w};
    float Tv[8] = {T0.x,T0.y,T0.z,T0.w,T1.x,T1.y,T1.z,T1.w};
    u16x8 ob;
    #pragma unroll
    for (int j=0;j<8;j++){
      float o = fmaxf(acc[j]*dn*Sv[j] + Tv[j], 0.f) + bf2f(hold[j]);
      ob[j] = f2bf(o);
    }
    *reinterpret_cast<u16x8*>(h + base) = ob;
  }
}

// ---------------- global mean pool (batch_idx sorted), bf16 h ----------------
__device__ __forceinline__ int lbound(const int* __restrict__ a, int n, int key){
  int lo = 0, hi = n;
  while (lo < hi){ int mid = (lo + hi) >> 1; if (a[mid] < key) lo = mid + 1; else hi = mid; }
  return lo;
}

__global__ __launch_bounds__(128) void k_pool(const unsigned short* __restrict__ h, const int* __restrict__ batch,
                                              float* __restrict__ g){
  int gi = blockIdx.x;
  int lo = lbound(batch, N_NODES, gi);
  int hi = lbound(batch, N_NODES, gi + 1);
  int t = threadIdx.x;
  float s0 = 0.f, s1 = 0.f;
  for (int n = lo; n < hi; ++n){
    unsigned u = *reinterpret_cast<const unsigned*>(h + (size_t)n*HDIM + 2*t);
    s0 += bf2f((unsigned short)(u & 0xffffu));
    s1 += bf2f((unsigned short)(u >> 16));
  }
  float inv = 1.0f / fmaxf((float)(hi - lo), 1.0f);
  g[(size_t)gi*HDIM + 2*t]     = s0 * inv;
  g[(size_t)gi*HDIM + 2*t + 1] = s1 * inv;
}

// ---------------- fused 3-layer property heads, GB graphs per block ----------------
__global__ __launch_bounds__(128) void k_heads(const float* __restrict__ g,
                                               const float* __restrict__ W1, const float* __restrict__ b1,
                                               const float* __restrict__ W2, const float* __restrict__ b2,
                                               const float* __restrict__ W3, const float* __restrict__ b3,
                                               float* __restrict__ out){
  int g0 = blockIdx.x * GB, p = blockIdx.y;
  __shared__ float gs[GB][HDIM];
  __shared__ float z1[GB][128];
  int t = threadIdx.x;
  #pragma unroll
  for (int gi=0; gi<GB; gi++){
    gs[gi][t]       = g[(size_t)(g0+gi)*HDIM + t];
    gs[gi][t + 128] = g[(size_t)(g0+gi)*HDIM + t + 128];
  }
  __syncthreads();

  const float* w1 = W1 + (size_t)p*HDIM*128;
  float a[GB];
  #pragma unroll
  for (int gi=0; gi<GB; gi++) a[gi] = 0.f;
  for (int i=0;i<HDIM;i++){
    float wv = w1[(size_t)i*128 + t];
    #pragma unroll
    for (int gi=0; gi<GB; gi++) a[gi] += gs[gi][i] * wv;
  }
  float b1v = b1[p*128 + t];
  #pragma unroll
  for (int gi=0; gi<GB; gi++) z1[gi][t] = fmaxf(a[gi] + b1v, 0.f);
  __syncthreads();

  if (t < 64){
    const float* w2 = W2 + (size_t)p*128*64;
    float a2[GB];
    #pragma unroll
    for (int gi=0; gi<GB; gi++) a2[gi] = 0.f;
    for (int i=0;i<128;i++){
      float wv = w2[(size_t)i*64 + t];
      #pragma unroll
      for (int gi=0; gi<GB; gi++) a2[gi] += z1[gi][i] * wv;
    }
    float w3v = W3[p*64 + t];
    float b2v = b2[p*64 + t];
    float b3v = b3[p];
    #pragma unroll
    for (int gi=0; gi<GB; gi++){
      float z2 = fmaxf(a2[gi] + b2v, 0.f);
      float v = z2 * w3v;
      #pragma unroll
      for (int off=32; off>0; off>>=1) v += __shfl_down(v, off, 64);
      if (t == 0) out[(size_t)(g0+gi)*NPROPS + p] = v + b3v;
    }
  }
}

// ---------------- launch ----------------
extern "C" void kernel_launch(void* const* d_in, const int* in_sizes, int n_in,
                              void* d_out, int out_size, void* d_ws, size_t ws_size,
                              hipStream_t stream){
  const float* x     = (const float*)d_in[0];
  const int*   ei    = (const int*)  d_in[1];
  const int*   batch = (const int*)  d_in[2];
  const float* embW  = (const float*)d_in[3];
  const float* embb  = (const float*)d_in[4];
  const float* gcnW  = (const float*)d_in[5];
  const float* gcnb  = (const float*)d_in[6];
  const float* bng   = (const float*)d_in[7];
  const float* bnb   = (const float*)d_in[8];
  const float* bnm   = (const float*)d_in[9];
  const float* bnv   = (const float*)d_in[10];
  const float* h1W   = (const float*)d_in[11];
  const float* h1b   = (const float*)d_in[12];
  const float* h2W   = (const float*)d_in[13];
  const float* h2b   = (const float*)d_in[14];
  const float* h3W   = (const float*)d_in[15];
  const float* h3b   = (const float*)d_in[16];
  float* out = (float*)d_out;

  char* w = (char*)d_ws;
  auto alloc = [&](size_t bytes)->char*{ char* p = w; w += (bytes + 255) & ~(size_t)255; return p; };
  unsigned short* h    = (unsigned short*)alloc((size_t)N_NODES*HDIM*2);   // bf16 h
  unsigned short* m    = (unsigned short*)alloc((size_t)N_NODES*HDIM*2);   // bf16 messages; reused as xb
  int*   cnt  = (int*)  alloc((size_t)N_NODES*4);
  int*   fill = (int*)  alloc((size_t)N_NODES*4);
  int*   rowp = (int*)  alloc((size_t)(N_NODES+1)*4);
  float* dinv = (float*)alloc((size_t)N_NODES*4);
  int2*  csr  = (int2*) alloc((size_t)N_EDGES*8);
  int*   part = (int*)  alloc(1024);
  float* gp   = (float*)alloc((size_t)N_GRAPHS*HDIM*4);
  unsigned short* embWt = (unsigned short*)alloc((size_t)NODE_DIMC*HDIM*2);
  unsigned short* gcnWt = (unsigned short*)alloc((size_t)NLAYERS*HDIM*HDIM*2);
  float* bnS  = (float*)alloc((size_t)NLAYERS*HDIM*4);
  float* bnT  = (float*)alloc((size_t)NLAYERS*HDIM*4);

  hipMemsetAsync(cnt, 0, (size_t)N_NODES*4, stream);

  const int EB = (N_EDGES + 255)/256;
  k_count<<<EB,256,0,stream>>>(ei, cnt);
  k_scan1<<<NBLK,256,0,stream>>>(cnt, rowp, part);
  k_scan2<<<1,256,0,stream>>>(part);
  k_scan3<<<NBLK,256,0,stream>>>(cnt, rowp, part, dinv, fill);
  k_fill<<<EB,256,0,stream>>>(ei, rowp, fill, dinv, csr);

  unsigned short* xb = m;
  k_prep<<<(PREP_TOTAL + 255)/256,256,0,stream>>>(x, xb, embW, embWt, gcnW, gcnWt,
                                                  gcnb, bng, bnb, bnm, bnv, bnS, bnT);

  const int RB64 = (N_NODES + 63)/64;   // 782 blocks, full-width tiles (A read once)
  k_mgemm<NODE_DIMC, true><<<RB64,256,0,stream>>>(xb, embWt, embb, h, N_NODES);

  for (int l = 0; l < NLAYERS; ++l){
    k_mgemm<HDIM, false><<<RB64,256,0,stream>>>(h, gcnWt + (size_t)l*HDIM*HDIM, nullptr, m, N_NODES);
    k_agg<<<(N_NODES+3)/4,256,0,stream>>>(m, rowp, csr, bnS + l*HDIM, bnT + l*HDIM, h);
  }

  k_pool<<<N_GRAPHS,128,0,stream>>>(h, batch, gp);
  k_heads<<<dim3((N_GRAPHS+GB-1)/GB,NPROPS),128,0,stream>>>(gp, h1W, h1b, h2W, h2b, h3W, h3b, out);
}